// Round 5
// baseline (163.652 us; speedup 1.0000x reference)
//
#include <hip/hip_runtime.h>

// Batched 1D linear interpolation with clamped extrapolation.
// t: [B,N] sorted fp32, v: [B,N] fp32, r: [B,M] fp32 -> out: [B,M] fp32
constexpr int B = 2048;
constexpr int N = 4096;
constexpr int M = 4096;
constexpr int K = 2048;  // buckets

// LDS = 16 KB st + 4 KB u16 lut = 20480 B -> 8 blocks/CU = 32 waves/CU (full).
// v is NOT staged: final v fetches go to global (L1/L2-served), trading ~200cyc
// latency (hidden by 8-wide ILP + full TLP) for 2x occupancy.
__global__ __launch_bounds__(256, 8) void interp_kernel(
    const float* __restrict__ t,
    const float* __restrict__ v,
    const float* __restrict__ r,
    float* __restrict__ out) {
    __shared__ float st[N];
    __shared__ unsigned short lut[K];  // lut[k] = first j with (int)(t[j]*K) >= k; else N

    const int b = blockIdx.x;
    const float* tb = t + (size_t)b * N;
    const float* vb = v + (size_t)b * N;
    const float* rb = r + (size_t)b * M;
    float* ob = out + (size_t)b * M;

    // Stage t with coalesced float4 loads; init lut.
    for (int i = threadIdx.x; i < N / 4; i += blockDim.x) {
        ((float4*)st)[i] = ((const float4*)tb)[i];
    }
    for (int k = threadIdx.x; k < K; k += blockDim.x) lut[k] = (unsigned short)N;
    __syncthreads();

    // Range-fill: element j claims buckets ((int)(t[j-1]*K), (int)(t[j]*K)].
    // Disjoint ranges -> no races; every covered k written exactly once.
    for (int j = threadIdx.x; j < N; j += blockDim.x) {
        int khi = (int)(st[j] * K);
        if (khi > K - 1) khi = K - 1;
        int klo = 0;
        if (j > 0) klo = (int)(st[j - 1] * K) + 1;
        for (int k = klo; k <= khi; ++k) lut[k] = (unsigned short)j;
    }
    __syncthreads();

    const float tfirst = st[0];
    const float tlast = st[N - 1];
    const float vfirst = vb[0];
    const float vlast = vb[N - 1];

    // Query loop: 8 queries/thread/iteration in phased SoA form for MLP/ILP.
    const float4* r4 = (const float4*)rb;
    float4* o4 = (float4*)ob;
    for (int base = 0; base < M / 4; base += 2 * 256) {
        const int ia = base + threadIdx.x;
        const int ib = ia + 256;
        const float4 qa = r4[ia];
        const float4 qb = r4[ib];
        float q[8] = {qa.x, qa.y, qa.z, qa.w, qb.x, qb.y, qb.z, qb.w};
        int lo[8], hi[8];

        // Phase 1: all 8 lut lookups issued together.
        #pragma unroll
        for (int j = 0; j < 8; ++j) {
            int k = (int)(q[j] * K);
            k = k < 0 ? 0 : (k > K - 1 ? K - 1 : k);
            lo[j] = lut[k];
            hi[j] = (k == K - 1) ? N : (int)lut[k + 1];
        }
        // Phase 2: branchless scan, 2 predicated steps + rare fallback
        // (mean advance ~1 for uniform t at N/K=2 density).
        #pragma unroll
        for (int j = 0; j < 8; ++j) {
            #pragma unroll
            for (int s = 0; s < 2; ++s) {
                const int safe = lo[j] < N - 1 ? lo[j] : N - 1;
                const bool adv = (lo[j] < hi[j]) && (st[safe] <= q[j]);
                lo[j] += adv ? 1 : 0;
            }
            while (lo[j] < hi[j] && st[lo[j]] <= q[j]) ++lo[j];
        }
        // Phase 3: final fetches (t from LDS, v from global/L2) + interp math.
        float o[8];
        #pragma unroll
        for (int j = 0; j < 8; ++j) {
            const int idx = lo[j] < 1 ? 1 : (lo[j] > N - 1 ? N - 1 : lo[j]);
            const float t0 = st[idx - 1];
            const float t1 = st[idx];
            const float v0 = vb[idx - 1];
            const float v1 = vb[idx];
            const float denom = (t1 == t0) ? 1.0f : (t1 - t0);
            float oo = v0 + (q[j] - t0) / denom * (v1 - v0);
            oo = (q[j] < tfirst) ? vfirst : oo;
            oo = (q[j] > tlast) ? vlast : oo;
            o[j] = oo;
        }
        o4[ia] = make_float4(o[0], o[1], o[2], o[3]);
        o4[ib] = make_float4(o[4], o[5], o[6], o[7]);
    }
}

extern "C" void kernel_launch(void* const* d_in, const int* in_sizes, int n_in,
                              void* d_out, int out_size, void* d_ws, size_t ws_size,
                              hipStream_t stream) {
    const float* t = (const float*)d_in[0];
    const float* v = (const float*)d_in[1];
    const float* r = (const float*)d_in[2];
    float* out = (float*)d_out;
    interp_kernel<<<B, 256, 0, stream>>>(t, v, r, out);
}

// Round 6
// 156.813 us; speedup vs baseline: 1.0436x; 1.0436x over previous
//
#include <hip/hip_runtime.h>

// Batched 1D linear interpolation with clamped extrapolation.
// t: [B,N] sorted fp32, v: [B,N] fp32, r: [B,M] fp32 -> out: [B,M] fp32
constexpr int B = 2048;
constexpr int N = 4096;
constexpr int M = 4096;
constexpr int K = 2048;   // buckets
constexpr int QPT = 16;   // queries per thread (M / 256), single pass

// LDS = 32 KB stv + ~4.1 KB lut = 4 blocks/CU (16 waves). launch_bounds(256,4)
// makes the 128-VGPR budget explicit so the compiler keeps all 16 query chains
// in flight (R5 lesson: (256,8) strangled VGPR to 24 and serialized the ILP;
// R4's default (256) capped at 64 and half-serialized it).
__global__ __launch_bounds__(256, 4) void interp_kernel(
    const float* __restrict__ t,
    const float* __restrict__ v,
    const float* __restrict__ r,
    float* __restrict__ out) {
    __shared__ float2 stv[N];              // interleaved (t, v): final fetch = one b64
    __shared__ unsigned short lut[K + 2];  // lut[k] = first j with (int)(t[j]*K) >= k; lut[K]=N sentinel

    const int b = blockIdx.x;
    const float* tb = t + (size_t)b * N;
    const float* vb = v + (size_t)b * N;
    const float* rb = r + (size_t)b * M;
    float* ob = out + (size_t)b * M;

    // Preload ALL queries first: their HBM latency hides behind staging + lut
    // build (they're only consumed after the second __syncthreads).
    const float4* r4 = (const float4*)rb;
    float4 qv[QPT / 4];
    #pragma unroll
    for (int p = 0; p < QPT / 4; ++p) qv[p] = r4[threadIdx.x + 256 * p];

    // Stage interleaved (t,v) with coalesced float4 global loads; init lut.
    for (int i = threadIdx.x; i < N / 4; i += 256) {
        const float4 t4 = ((const float4*)tb)[i];
        const float4 v4 = ((const float4*)vb)[i];
        stv[4 * i + 0] = make_float2(t4.x, v4.x);
        stv[4 * i + 1] = make_float2(t4.y, v4.y);
        stv[4 * i + 2] = make_float2(t4.z, v4.z);
        stv[4 * i + 3] = make_float2(t4.w, v4.w);
    }
    for (int k = threadIdx.x; k <= K; k += 256) lut[k] = (unsigned short)N;
    __syncthreads();

    // Range-fill: element j claims buckets ((int)(t[j-1]*K), (int)(t[j]*K)].
    // Disjoint ranges -> no races; every covered k written exactly once.
    // lut[K] is never written -> stays N (sentinel for hi at k=K-1).
    for (int j = threadIdx.x; j < N; j += 256) {
        int khi = (int)(stv[j].x * K);
        if (khi > K - 1) khi = K - 1;
        int klo = 0;
        if (j > 0) klo = (int)(stv[j - 1].x * K) + 1;
        for (int k = klo; k <= khi; ++k) lut[k] = (unsigned short)j;
    }
    __syncthreads();

    const float tfirst = stv[0].x;
    const float vfirst = stv[0].y;
    const float tlast = stv[N - 1].x;
    const float vlast = stv[N - 1].y;

    float q[QPT];
    #pragma unroll
    for (int p = 0; p < QPT / 4; ++p) {
        q[4 * p + 0] = qv[p].x;
        q[4 * p + 1] = qv[p].y;
        q[4 * p + 2] = qv[p].z;
        q[4 * p + 3] = qv[p].w;
    }

    int lo[QPT], hi[QPT];
    // Phase 1: all lut lookups issued together (independent).
    #pragma unroll
    for (int j = 0; j < QPT; ++j) {
        int k = (int)(q[j] * K);
        k = k < 0 ? 0 : (k > K - 1 ? K - 1 : k);
        lo[j] = (int)lut[k];
        hi[j] = (int)lut[k + 1];  // sentinel makes k=K-1 safe
    }
    // Phase 2: branchless scan, 2 predicated steps + rare fallback
    // (mean advance ~1 for uniform t at N/K=2 knots/bucket).
    #pragma unroll
    for (int j = 0; j < QPT; ++j) {
        #pragma unroll
        for (int s = 0; s < 2; ++s) {
            const int safe = lo[j] < N - 1 ? lo[j] : N - 1;
            const bool adv = (lo[j] < hi[j]) && (stv[safe].x <= q[j]);
            lo[j] += adv ? 1 : 0;
        }
        while (lo[j] < hi[j] && stv[lo[j]].x <= q[j]) ++lo[j];
    }
    // Phase 3: final b64 fetches + interp math.
    float o[QPT];
    #pragma unroll
    for (int j = 0; j < QPT; ++j) {
        const int idx = lo[j] < 1 ? 1 : (lo[j] > N - 1 ? N - 1 : lo[j]);
        const float2 p0 = stv[idx - 1];
        const float2 p1 = stv[idx];
        const float denom = (p1.x == p0.x) ? 1.0f : (p1.x - p0.x);
        float oo = p0.y + (q[j] - p0.x) / denom * (p1.y - p0.y);
        oo = (q[j] < tfirst) ? vfirst : oo;
        oo = (q[j] > tlast) ? vlast : oo;
        o[j] = oo;
    }
    float4* o4 = (float4*)ob;
    #pragma unroll
    for (int p = 0; p < QPT / 4; ++p) {
        o4[threadIdx.x + 256 * p] =
            make_float4(o[4 * p + 0], o[4 * p + 1], o[4 * p + 2], o[4 * p + 3]);
    }
}

extern "C" void kernel_launch(void* const* d_in, const int* in_sizes, int n_in,
                              void* d_out, int out_size, void* d_ws, size_t ws_size,
                              hipStream_t stream) {
    const float* t = (const float*)d_in[0];
    const float* v = (const float*)d_in[1];
    const float* r = (const float*)d_in[2];
    float* out = (float*)d_out;
    interp_kernel<<<B, 256, 0, stream>>>(t, v, r, out);
}

// Round 7
// 152.480 us; speedup vs baseline: 1.0733x; 1.0284x over previous
//
#include <hip/hip_runtime.h>

// Batched 1D linear interpolation with clamped extrapolation.
// t: [B,N] sorted fp32, v: [B,N] fp32, r: [B,M] fp32 -> out: [B,M] fp32
constexpr int B = 2048;
constexpr int N = 4096;
constexpr int M = 4096;
constexpr int K = 4096;  // buckets; lambda = N/K = 1 knot/bucket
constexpr int QPT = 4;   // queries per pass; 4 passes (keeps live state ~50 regs)

// LDS = 32 KB stv + 8 KB u16 lut = 40960 B -> 4 blocks/CU (16 waves).
// Search chain depth is 2 LDS levels: lut[k] -> 3 parallel b128 window loads;
// the bracketing pair is selected by a VALU compare cascade (no serial scan).
__global__ __launch_bounds__(256, 4) void interp_kernel(
    const float* __restrict__ t,
    const float* __restrict__ v,
    const float* __restrict__ r,
    float* __restrict__ out) {
    __shared__ __align__(16) float2 stv[N];  // interleaved (t, v)
    __shared__ unsigned short lut[K];        // lut[k] = first j with (int)(t[j]*K) >= k; else N

    const int b = blockIdx.x;
    const float* tb = t + (size_t)b * N;
    const float* vb = v + (size_t)b * N;
    const float* rb = r + (size_t)b * M;
    float* ob = out + (size_t)b * M;

    // Preload ALL queries up-front: HBM latency hides behind staging + lut build.
    const float4* r4 = (const float4*)rb;
    float4 qv[4];
    #pragma unroll
    for (int p = 0; p < 4; ++p) qv[p] = r4[threadIdx.x + 256 * p];

    // Stage interleaved (t,v) via float4 global loads + b128 LDS writes; init lut.
    for (int i = threadIdx.x; i < N / 4; i += 256) {
        const float4 t4 = ((const float4*)tb)[i];
        const float4 v4 = ((const float4*)vb)[i];
        float4* d = (float4*)&stv[4 * i];
        d[0] = make_float4(t4.x, v4.x, t4.y, v4.y);
        d[1] = make_float4(t4.z, v4.z, t4.w, v4.w);
    }
    for (int k = threadIdx.x; k < K; k += 256) lut[k] = (unsigned short)N;
    __syncthreads();

    // Range-fill: element j claims buckets ((int)(t[j-1]*K), (int)(t[j]*K)].
    // Disjoint ranges -> no races; every covered k written exactly once.
    for (int j = threadIdx.x; j < N; j += 256) {
        int khi = (int)(stv[j].x * K);
        if (khi > K - 1) khi = K - 1;
        const int klo = (j == 0) ? 0 : (int)(stv[j - 1].x * K) + 1;
        for (int k = klo; k <= khi; ++k) lut[k] = (unsigned short)j;
    }
    __syncthreads();

    const float tfirst = stv[0].x;
    const float vfirst = stv[0].y;
    const float tlast = stv[N - 1].x;
    const float vlast = stv[N - 1].y;
    const float4* S4 = (const float4*)stv;
    float4* o4 = (float4*)ob;

    #pragma unroll
    for (int pass = 0; pass < 4; ++pass) {
        const float4 qp = qv[pass];
        float q[QPT] = {qp.x, qp.y, qp.z, qp.w};
        int w[QPT];
        float4 W0[QPT], W1[QPT], W2[QPT];

        // Phase 1+2: lut lookup then 3 parallel b128 window loads per query.
        #pragma unroll
        for (int j = 0; j < QPT; ++j) {
            int k = (int)(q[j] * K);
            k = k < 0 ? 0 : (k > K - 1 ? K - 1 : k);
            int ww = (int)lut[k] - 1;
            ww = ww < 0 ? 0 : (ww > N - 6 ? N - 6 : ww);
            ww &= ~1;  // 16 B alignment for b128 window loads
            w[j] = ww;
            const float4* p = S4 + (ww >> 1);
            W0[j] = p[0];
            W1[j] = p[1];
            W2[j] = p[2];
        }
        // Phase 3: prefix-compare cascade selects the bracketing pair; math.
        float o[QPT];
        #pragma unroll
        for (int j = 0; j < QPT; ++j) {
            const float qq = q[j];
            const float2 P0 = make_float2(W0[j].x, W0[j].y);
            const float2 P1 = make_float2(W0[j].z, W0[j].w);
            const float2 P2 = make_float2(W1[j].x, W1[j].y);
            const float2 P3 = make_float2(W1[j].z, W1[j].w);
            const float2 P4 = make_float2(W2[j].x, W2[j].y);
            const float2 P5 = make_float2(W2[j].z, W2[j].w);
            // b_i monotone (t sorted): #true = searchsorted_right(q) - w - 1.
            const bool b1 = P1.x <= qq, b2 = P2.x <= qq, b3 = P3.x <= qq;
            const bool b4 = P4.x <= qq, b5 = P5.x <= qq;
            float2 plo = P0, phi = P1;
            plo = b1 ? P1 : plo; phi = b1 ? P2 : phi;
            plo = b2 ? P2 : plo; phi = b2 ? P3 : phi;
            plo = b3 ? P3 : plo; phi = b3 ? P4 : phi;
            plo = b4 ? P4 : plo; phi = b4 ? P5 : phi;
            if (b5 && qq < tlast) {  // rare (~0.1%): answer beyond the window
                int c = w[j] + 6;
                while (c < N && stv[c].x <= qq) ++c;  // stops <= N-1 since qq < tlast
                plo = stv[c - 1];
                phi = stv[c];
            }
            const float denom = (phi.x == plo.x) ? 1.0f : (phi.x - plo.x);
            float oo = plo.y + (qq - plo.x) / denom * (phi.y - plo.y);
            oo = (qq < tfirst) ? vfirst : oo;   // west: interp path handles ==
            oo = (qq >= tlast) ? vlast : oo;    // east: == gives vlast (matches ref)
            o[j] = oo;
        }
        o4[threadIdx.x + 256 * pass] = make_float4(o[0], o[1], o[2], o[3]);
    }
}

extern "C" void kernel_launch(void* const* d_in, const int* in_sizes, int n_in,
                              void* d_out, int out_size, void* d_ws, size_t ws_size,
                              hipStream_t stream) {
    const float* t = (const float*)d_in[0];
    const float* v = (const float*)d_in[1];
    const float* r = (const float*)d_in[2];
    float* out = (float*)d_out;
    interp_kernel<<<B, 256, 0, stream>>>(t, v, r, out);
}